// Round 6
// baseline (610.745 us; speedup 1.0000x reference)
//
#include <hip/hip_runtime.h>

typedef _Float16 half_t;
typedef _Float16 half8 __attribute__((ext_vector_type(8)));
typedef __fp16 fp16x2 __attribute__((ext_vector_type(2)));   // native type of cvt_pkrtz/fdot2
typedef float f32x16 __attribute__((ext_vector_type(16)));
typedef float f32x4v __attribute__((ext_vector_type(4)));
typedef unsigned uint2v __attribute__((ext_vector_type(2)));

#define MFMA32(A, B, C) __builtin_amdgcn_mfma_f32_32x32x16_f16(A, B, C, 0, 0, 0)

#if __has_builtin(__builtin_amdgcn_exp2f)
#define EXP2F(x) __builtin_amdgcn_exp2f(x)
#else
#define EXP2F(x) exp2f(x)
#endif

static constexpr int S = 2048;
static constexpr int D = 1024;
// log2(e)/8: folds the 1/sqrt(64) score scale and exp->exp2 change of base into Q
static constexpr float QSCALE = 0.18033688011112042f;

// R12 LESSON: hipLaunchCooperativeKernel + cg::grid.sync() produced racy/absent
// synchronization in this harness (absmax 0.19 direct / 468 under graph).
// R13: same fusion, but plain launch + hand-rolled grid barrier:
//   - 512 blocks x 512 thr x 64 KB LDS = exactly 2 blocks/CU -> all co-resident
//     by capacity; __launch_bounds__(512,4) pins VGPR<=128 so occupancy holds.
//   - barrier: per-phase counter+flag in d_ws (zeroed via hipMemsetAsync on the
//     stream before launch, graph-capturable), device-scope atomics,
//     __threadfence() release before arrive + acquire after -> also handles the
//     cross-XCD L2 staleness the guide warns about.
// Phase bodies are verbatim from the verified 4-kernel pipeline (R11 attn).

// async global->LDS, 16B per lane; LDS dest = wave-uniform base + lane*16
__device__ __forceinline__ void gload_lds16(const void* g, void* l) {
    __builtin_amdgcn_global_load_lds(
        (const __attribute__((address_space(1))) unsigned int*)g,
        (__attribute__((address_space(3))) unsigned int*)l, 16, 0, 0);
}

// ---------------- grid barrier (counters at bar, 64B-strided slots) ----------------
__device__ __forceinline__ void gridbar(unsigned* bar, int idx) {
    __syncthreads();                     // block done with phase
    if (threadIdx.x == 0) {
        __threadfence();                 // release: flush this block's writes
        unsigned* cnt  = bar + idx * 16;
        unsigned* flag = bar + idx * 16 + 8;
        unsigned old = atomicAdd(cnt, 1u);   // device-scope by default
        if (old == 511u) {
            __hip_atomic_store(flag, 1u, __ATOMIC_RELEASE, __HIP_MEMORY_SCOPE_AGENT);
        } else {
            while (__hip_atomic_load(flag, __ATOMIC_ACQUIRE, __HIP_MEMORY_SCOPE_AGENT) == 0u)
                __builtin_amdgcn_s_sleep(2);
        }
    }
    __syncthreads();                     // rest of block waits on lane 0
    __threadfence();                     // acquire: invalidate stale L1/L2 lines
}

// ---------------- 128x128 GEMM tile body (4-wave sub-block) ----------------
// t in 0..255 within the sub-block; sm = 32 KB LDS for this sub-block.
// All __syncthreads() are block-wide: both sub-blocks run identical trip
// counts, and inactive sub-blocks still execute every barrier.
__device__ __forceinline__ void gemm_tile_qkv(
    int job, int t, char* sm, bool active,
    const half_t* __restrict__ a0, const half_t* __restrict__ a1, const half_t* __restrict__ a2,
    const half_t* __restrict__ wt,
    const float* __restrict__ b0, const float* __restrict__ b1, const float* __restrict__ b2,
    half_t* __restrict__ qh, half_t* __restrict__ kh, half_t* __restrict__ vtb)
{
    half_t* As = (half_t*)sm;
    half_t* Bs = (half_t*)(sm + 16384);
    int z = job >> 8;
    int L = job & 255;
    const half_t* A = (z == 0) ? a0 : (z == 1) ? a1 : a2;
    const half_t* BT = wt + (size_t)z * 1048576;
    const float* bias = (z == 0) ? b0 : (z == 1) ? b1 : b2;
    int w = L >> 3;
    int mt = (L & 7) * 4 + (w & 3);
    int nt8 = w >> 2;
    int m0 = mt * 128, n0 = nt8 * 128;
    int lane = t & 63, wave = t >> 6;
    int ml = lane & 31, hi = lane >> 5;
    int wm = (wave & 1) * 64, wn = (wave >> 1) * 64;

    f32x16 acc00 = {}, acc01 = {}, acc10 = {}, acc11 = {};

    for (int kt = 0; kt < 16; ++kt) {
        __syncthreads();
        if (active) {
            const half_t* Aslab = A + ((size_t)(mt * 16 + kt)) * 8192;
            const half_t* Bslab = BT + ((size_t)(nt8 * 16 + kt)) * 8192;
#pragma unroll
            for (int j = 0; j < 4; ++j) {
                int s = wave * 4 + j;
                gload_lds16(Aslab + s * 512 + lane * 8, As + s * 512);
                gload_lds16(Bslab + s * 512 + lane * 8, Bs + s * 512);
            }
        }
        __syncthreads();
        if (active) {
#pragma unroll
            for (int ks = 0; ks < 4; ++ks) {
                int co = (2 * ks + hi) * 128;
                half8 af0 = *(const half8*)(As + (size_t)(co + wm + ml) * 8);
                half8 af1 = *(const half8*)(As + (size_t)(co + wm + 32 + ml) * 8);
                half8 bf0 = *(const half8*)(Bs + (size_t)(co + wn + ml) * 8);
                half8 bf1 = *(const half8*)(Bs + (size_t)(co + wn + 32 + ml) * 8);
                acc00 = MFMA32(af0, bf0, acc00);
                acc01 = MFMA32(af0, bf1, acc01);
                acc10 = MFMA32(af1, bf0, acc10);
                acc11 = MFMA32(af1, bf1, acc11);
            }
        }
    }

    // ---- epilogue: C tile -> swizzled LDS buf -> coalesced blocked global ----
    __syncthreads();
    half_t* buf = (half_t*)sm;
    if (active) {
#pragma unroll
        for (int nt = 0; nt < 2; ++nt) {
            int nl = wn + nt * 32 + ml;
            float bv = bias[n0 + nl];
            int hh = nl >> 6, c = (nl >> 3) & 7, j = nl & 7, dd = nl & 63;
#pragma unroll
            for (int mt2 = 0; mt2 < 2; ++mt2) {
                f32x16 av = (mt2 == 0) ? (nt == 0 ? acc00 : acc01) : (nt == 0 ? acc10 : acc11);
#pragma unroll
                for (int r = 0; r < 16; ++r) {
                    int rl = wm + mt2 * 32 + 4 * hi + (r & 3) + 8 * (r >> 2);
                    float v = av[r] + bv;
                    if (z == 0) v *= QSCALE;
                    if (z <= 1) {
                        buf[((rl * 2 + hh) * 8 + (c ^ (rl & 7))) * 8 + j] = (half_t)v;
                    } else {
                        int cc = rl >> 3, js = rl & 7;
                        buf[((dd * 2 + hh) * 16 + (cc ^ (dd & 7))) * 8 + js] = (half_t)v;
                    }
                }
            }
        }
    }
    __syncthreads();
    if (active) {
        int bq_ = m0 >> 11, skt = (m0 >> 7) & 15, h0 = n0 >> 6;
        half_t* dstm = (z == 0) ? qh : (z == 1) ? kh : vtb;
#pragma unroll
        for (int i = 0; i < 8; ++i) {
            int o = t + 256 * i;        // 2048 x 16B chunks
            int hh = o >> 10;
            half_t* gdst = dstm + ((size_t)(bq_ * 16 + h0 + hh)) * 131072 + (size_t)skt * 8192;
            half8 v8;
            int off;
            if (z <= 1) {
                int c = (o >> 7) & 7, r = o & 127;
                v8 = *(const half8*)(buf + (((r * 2 + hh) * 8 + (c ^ (r & 7))) * 8));
                off = (c * 128 + r) * 8;
            } else {
                int cc = (o >> 6) & 15, dd = o & 63;
                v8 = *(const half8*)(buf + (((dd * 2 + hh) * 16 + (cc ^ (dd & 7))) * 8));
                off = (cc * 64 + dd) * 8;
            }
            *(half8*)(gdst + off) = v8;
        }
    }
}

__device__ __forceinline__ void gemm_tile_out(
    int L, int t, char* sm, bool active,
    const half_t* __restrict__ A, const half_t* __restrict__ BT,
    const float* __restrict__ bias, float* __restrict__ out)
{
    half_t* As = (half_t*)sm;
    half_t* Bs = (half_t*)(sm + 16384);
    int w = L >> 3;
    int mt = (L & 7) * 4 + (w & 3);
    int nt8 = w >> 2;
    int m0 = mt * 128, n0 = nt8 * 128;
    int lane = t & 63, wave = t >> 6;
    int ml = lane & 31, hi = lane >> 5;
    int wm = (wave & 1) * 64, wn = (wave >> 1) * 64;

    f32x16 acc00 = {}, acc01 = {}, acc10 = {}, acc11 = {};

    for (int kt = 0; kt < 16; ++kt) {
        __syncthreads();
        if (active) {
            const half_t* Aslab = A + ((size_t)(mt * 16 + kt)) * 8192;
            const half_t* Bslab = BT + ((size_t)(nt8 * 16 + kt)) * 8192;
#pragma unroll
            for (int j = 0; j < 4; ++j) {
                int s = wave * 4 + j;
                gload_lds16(Aslab + s * 512 + lane * 8, As + s * 512);
                gload_lds16(Bslab + s * 512 + lane * 8, Bs + s * 512);
            }
        }
        __syncthreads();
        if (active) {
#pragma unroll
            for (int ks = 0; ks < 4; ++ks) {
                int co = (2 * ks + hi) * 128;
                half8 af0 = *(const half8*)(As + (size_t)(co + wm + ml) * 8);
                half8 af1 = *(const half8*)(As + (size_t)(co + wm + 32 + ml) * 8);
                half8 bf0 = *(const half8*)(Bs + (size_t)(co + wn + ml) * 8);
                half8 bf1 = *(const half8*)(Bs + (size_t)(co + wn + 32 + ml) * 8);
                acc00 = MFMA32(af0, bf0, acc00);
                acc01 = MFMA32(af0, bf1, acc01);
                acc10 = MFMA32(af1, bf0, acc10);
                acc11 = MFMA32(af1, bf1, acc11);
            }
        }
    }

    if (active) {
#pragma unroll
        for (int nt = 0; nt < 2; ++nt) {
            int n = n0 + wn + nt * 32 + ml;
            float bv = bias[n];
#pragma unroll
            for (int mt2 = 0; mt2 < 2; ++mt2) {
                f32x16 av = (mt2 == 0) ? (nt == 0 ? acc00 : acc01) : (nt == 0 ? acc10 : acc11);
                int rbase = m0 + wm + mt2 * 32 + 4 * hi;
#pragma unroll
                for (int r = 0; r < 16; ++r) {
                    int row = rbase + (r & 3) + 8 * (r >> 2);
                    out[(size_t)row * D + n] = av[r] + bv;
                }
            }
        }
    }
}

// ---------------- the fused kernel (plain launch, hand-rolled grid barrier) ----------------
__global__ __launch_bounds__(512, 4) void fused(
    const float* __restrict__ qx, const float* __restrict__ kx, const float* __restrict__ vx,
    const float* __restrict__ Wq, const float* __restrict__ bq,
    const float* __restrict__ Wk, const float* __restrict__ bk,
    const float* __restrict__ Wv, const float* __restrict__ bv,
    const float* __restrict__ Wo, const float* __restrict__ bo,
    float* __restrict__ out,
    half_t* __restrict__ qxh, half_t* __restrict__ kxh, half_t* __restrict__ vxh,
    half_t* __restrict__ wt, half_t* __restrict__ qh, half_t* __restrict__ kh,
    half_t* __restrict__ vtr, half_t* __restrict__ ctx, unsigned* __restrict__ bar)
{
    __shared__ char smem[65536];
    int bid = blockIdx.x;
    int t = threadIdx.x;
    int sb = t >> 8, t256 = t & 255;

    // ========== phase 1: fp32 -> fp16 blocked conversion (2048 jobs) ==========
    for (int job = bid; job < 2048; job += 512) {
        __syncthreads();   // protect LDS from previous job's readers
        int y = job >> 9, x = job & 511;
        if (y < 3) {
            float (*tile)[65] = (float(*)[65])smem;
            const float* src = (y == 0) ? qx : (y == 1) ? kx : vx;
            half_t* dst = (y == 0) ? qxh : (y == 1) ? kxh : vxh;
            int mt = x >> 4, kt = x & 15;
            const float* sbase = src + (size_t)(mt * 128) * D + kt * 64;
            int rr = t >> 4, col = (t & 15) * 4;
#pragma unroll
            for (int p = 0; p < 4; ++p) {
                int row = rr + p * 32;
                f32x4v v = *(const f32x4v*)(sbase + (size_t)row * D + col);
                tile[row][col] = v[0]; tile[row][col + 1] = v[1];
                tile[row][col + 2] = v[2]; tile[row][col + 3] = v[3];
            }
            __syncthreads();
            int c = t >> 6, r0 = t & 63;
            half_t* dbase = dst + ((size_t)(mt * 16 + kt)) * 8192;
#pragma unroll
            for (int i = 0; i < 2; ++i) {
                int row = r0 + 64 * i;
                half8 h;
#pragma unroll
                for (int j = 0; j < 8; ++j) h[j] = (half_t)tile[row][c * 8 + j];
                *(half8*)(dbase + ((size_t)c * 128 + row) * 8) = h;
            }
        } else {
            float (*tile)[129] = (float(*)[129])smem;
            int w = x >> 7;
            const float* W = (w == 0) ? Wq : (w == 1) ? Wk : (w == 2) ? Wv : Wo;
            int idx = x & 127;
            int nt = idx >> 4, kt = idx & 15;
            const float* sbase = W + (size_t)(kt * 64) * D + nt * 128;
            int kr = t >> 5, col = (t & 31) * 4;
#pragma unroll
            for (int p = 0; p < 4; ++p) {
                int k = kr + p * 16;
                f32x4v v = *(const f32x4v*)(sbase + (size_t)k * D + col);
                tile[k][col] = v[0]; tile[k][col + 1] = v[1];
                tile[k][col + 2] = v[2]; tile[k][col + 3] = v[3];
            }
            __syncthreads();
            int c = t >> 6, r0 = t & 63;
            half_t* dbase = wt + (size_t)w * 1048576 + ((size_t)(nt * 16 + kt)) * 8192;
#pragma unroll
            for (int i = 0; i < 2; ++i) {
                int n = r0 + 64 * i;
                half8 h;
#pragma unroll
                for (int j = 0; j < 8; ++j) h[j] = (half_t)tile[c * 8 + j][n];
                *(half8*)(dbase + ((size_t)c * 128 + n) * 8) = h;
            }
        }
    }
    gridbar(bar, 0);

    // ========== phase 2: QKV projection GEMMs (768 jobs, 2 sub-blocks/block) ==========
    {
        int job; bool active;
        if (sb == 0) { job = bid; active = true; }                       // z = 0,1
        else { job = 512 + (bid >> 1); active = ((bid & 1) == 0); }      // z = 2 on even blocks
        gemm_tile_qkv(active ? job : 0, t256, smem + (size_t)sb * 32768, active,
                      qxh, kxh, vxh, wt, bq, bk, bv, qh, kh, vtr);
    }
    gridbar(bar, 1);

    // ========== phase 3: fused attention (512 jobs, 1 per block; R11 body) ==========
    {
        int L = bid;
        int slot = L >> 3;
        int bh = (L & 7) + 8 * (slot >> 4);
        int sq = slot & 15;
        int b_ = bh >> 4, h = bh & 15;

        int lane = t & 63, wave = t >> 6;
        int ml = lane & 31, hi = lane >> 5;
        int qq = wave & 3, th = wave >> 2;
        const half_t* qslab = qh + (size_t)bh * 131072 + (size_t)sq * 8192;
        const half_t* khead = kh + (size_t)bh * 131072;
        const half_t* vhead = vtr + (size_t)bh * 131072;

        // stage Q into Ks(1) region and K/V tile 0 into buf0 (single barrier)
        {
            half_t* QB = (half_t*)(smem + 32768);
            half_t* K0 = (half_t*)(smem);
            half_t* V0 = (half_t*)(smem + 16384);
#pragma unroll
            for (int j = 0; j < 2; ++j) {
                int s = wave * 2 + j;
                gload_lds16(qslab + s * 512 + lane * 8, QB + s * 512);
                gload_lds16(khead + s * 512 + lane * 8, K0 + s * 512);
                gload_lds16(vhead + s * 512 + lane * 8, V0 + s * 512);
            }
        }
        __syncthreads();
        half8 qf[4];
        {
            half_t* QB = (half_t*)(smem + 32768);
#pragma unroll
            for (int ks = 0; ks < 4; ++ks)
                qf[ks] = *(const half8*)(QB + ((size_t)((2 * ks + hi) * 128 + qq * 32 + ml)) * 8);
        }
        __syncthreads();   // all qf reads complete before buf1 (= QB region) is restaged

        f32x16 oacc[2] = {};
        float lsumA = 0.0f, lsumB = 0.0f;
        fp16x2 one2; one2.x = (__fp16)1.0f; one2.y = (__fp16)1.0f;
        const f32x16 sinit = {-10.0f, -10.0f, -10.0f, -10.0f, -10.0f, -10.0f, -10.0f, -10.0f,
                              -10.0f, -10.0f, -10.0f, -10.0f, -10.0f, -10.0f, -10.0f, -10.0f};

        int t0 = th * 2, t1 = th * 2 + 1;

        for (int it = 0; it < 16; ++it) {
            int bb = it & 1;
            if (it < 15) {   // prefetch next tile into the other buffer (overlaps compute)
                const half_t* kslab = khead + (size_t)(it + 1) * 8192;
                const half_t* vslab = vhead + (size_t)(it + 1) * 8192;
                half_t* Kd = (half_t*)(smem + (bb ^ 1) * 32768);
                half_t* Vd = (half_t*)(smem + 16384 + (bb ^ 1) * 32768);
#pragma unroll
                for (int j = 0; j < 2; ++j) {
                    int s = wave * 2 + j;
                    gload_lds16(kslab + s * 512 + lane * 8, Kd + s * 512);
                    gload_lds16(vslab + s * 512 + lane * 8, Vd + s * 512);
                }
            }
            half_t* Ks  = (half_t*)(smem + bb * 32768);
            half_t* VTs = (half_t*)(smem + 16384 + bb * 32768);

            // ---- QK for both k-subtiles, interleaved ----
            f32x16 sv0 = sinit, sv1 = sinit;
            __builtin_amdgcn_s_setprio(1);
#pragma unroll
            for (int ks = 0; ks < 4; ++ks) {
                half8 kf0 = *(const half8*)(Ks + ((size_t)((2 * ks + hi) * 128 + t0 * 32 + ml)) * 8);
                half8 kf1 = *(const half8*)(Ks + ((size_t)((2 * ks + hi) * 128 + t1 * 32 + ml)) * 8);
                sv0 = MFMA32(kf0, qf[ks], sv0);
                sv1 = MFMA32(kf1, qf[ks], sv1);
            }
            __builtin_amdgcn_s_setprio(0);

            // ---- SM0 ----
            unsigned pkv0[8];
            {
                float lsA = lsumA;
#pragma unroll
                for (int j = 0; j < 8; ++j) {
                    float pa = EXP2F(sv0[2 * j]);
                    float pb = EXP2F(sv0[2 * j + 1]);
#if __has_builtin(__builtin_amdgcn_cvt_pkrtz)
                    fp16x2 h2 = __builtin_amdgcn_cvt_pkrtz(pa, pb);
#else
                    fp16x2 h2; h2.x = (__fp16)pa; h2.y = (__fp16)pb;
#endif
                    pkv0[j] = __builtin_bit_cast(unsigned, h2);
#if __has_builtin(__builtin_amdgcn_fdot2)
                    lsA = __builtin_amdgcn_fdot2(h2, one2, lsA, false);
#else
                    lsA += pa + pb;
#endif
                }
                lsumA = lsA;
            }

            // ---- PV0 ----
#pragma unroll
            for (int kp = 0; kp < 2; ++kp) {
                union { unsigned u[4]; half8 h; } fr;
#if __has_builtin(__builtin_amdgcn_permlane32_swap)
                uint2v w0 = __builtin_amdgcn_permlane32_swap(pkv0[4 * kp + 0], pkv0[4 * kp + 2], false, false);
                uint2v w1 = __builtin_amdgcn_permlane32_swap(pkv0[4 * kp + 1], pkv0[4 * kp + 3], false, false);
                fr.u[0] = w0.x; fr.u[1] = w1.x; fr.u[2] = w0.y; fr.u[3] = w1.y;
#else
                unsigned e0 = pkv0[4 * kp + 0], e1 = pkv0[4 * kp + 1];
                unsigned o0 = pkv0[4 * kp + 2], o1 = pkv0[4 * kp + 3];
                unsigned s0u = hi ? e0 : o0, s1u = hi ? e1 : o1;
                unsigned k0u = hi ? o0 : e0, k1u = hi ? o1 : e1;
                unsigned r0 = __shfl_xor(s0u, 32, 64);
                unsigned r1 = __shfl_xor(s1u, 32, 64);
                fr.u[0] = hi ? r0 : k0u; fr.u[1] = hi ? r1 : k1u;
                fr.u[2] = hi ? k0u : r0; fr.u[3] = hi ? k1u : r1;
#endif
                __builtin_amdgcn_s_setprio(1);
#pragma unroll
                for (int dt = 0; dt < 2; ++dt) {
                    half8 vf = *(const half8*)(VTs + ((size_t)((4 * t0 + 2 * kp + hi) * 64 + dt * 32 + ml)) * 8);
                    oacc[dt] = MFMA32(fr.h, vf, oacc[dt]);
                }
                __builtin_amdgcn_s_setprio(0);
            }

            // ---- SM1 ----
            unsigned pkv1[8];
            {
                float lsB = lsumB;
#pragma unroll
                for (int j = 0; j < 8; ++j) {
                    float pa = EXP2F(sv1[2 * j]);
                    float pb = EXP2F(sv1[2 * j + 1]);
#if __has_builtin(__builtin_amdgcn_cvt_pkrtz)
                    fp16x2 h2 = __builtin_amdgcn_cvt_pkrtz(pa, pb);
#else
                    fp16x2 h2; h2.x = (__fp16)pa; h2.y = (__fp16)pb;
#endif
                    pkv1[j] = __builtin_bit_cast(unsigned, h2);
#if __has_builtin(__builtin_amdgcn_fdot2)
                    lsB = __builtin_amdgcn_fdot2(h2, one2, lsB, false);
#else
                    lsB += pa + pb;
#endif
                }
                lsumB = lsB;
            }

            // ---- PV1 ----
#pragma unroll
            for (int kp = 0; kp < 2; ++kp) {
                union { unsigned u[4]; half8 h; } fr;
#if __has_builtin(__builtin_amdgcn_permlane32_swap)
                uint2v w0 = __builtin_amdgcn_permlane32_swap(pkv1[4 * kp + 0], pkv1[4 * kp + 2], false, false);
                uint2v w1 = __builtin_amdgcn_permlane32_swap(pkv1[4 * kp + 1], pkv1[4 * kp + 3], false, false);
                fr.u[0] = w0.x; fr.u[1] = w1.x; fr.u[2] = w0.y; fr.u[3] = w1.y;
#else
                unsigned e0 = pkv1[4 * kp + 0], e1 = pkv1[4 * kp + 1];
                unsigned o0 = pkv1[4 * kp + 2], o1 = pkv1[4 * kp + 3];
                unsigned s0u = hi ? e0 : o0, s1u = hi ? e1 : o1;
                unsigned k0u = hi ? o0 : e0, k1u = hi ? o1 : e1;
                unsigned r0 = __shfl_xor(s0u, 32, 64);
                unsigned r1 = __shfl_xor(s1u, 32, 64);
                fr.u[0] = hi ? r0 : k0u; fr.u[1] = hi ? r1 : k1u;
                fr.u[2] = hi ? k0u : r0; fr.u[3] = hi ? k1u : r1;
#endif
                __builtin_amdgcn_s_setprio(1);
#pragma unroll
                for (int dt = 0; dt < 2; ++dt) {
                    half8 vf = *(const half8*)(VTs + ((size_t)((4 * t1 + 2 * kp + hi) * 64 + dt * 32 + ml)) * 8);
                    oacc[dt] = MFMA32(fr.h, vf, oacc[dt]);
                }
                __builtin_amdgcn_s_setprio(0);
            }

            __syncthreads();   // drains the it+1 prefetch
        }

        // ---- epilogue: combine th partials, normalize, store ----
        float lsum = lsumA + lsumB;
        float lt = lsum + __shfl_xor(lsum, 32, 64);

        float* OB = (float*)(smem + (size_t)qq * 8192);
        if (th == 1) {
#pragma unroll
            for (int dt = 0; dt < 2; ++dt)
#pragma unroll
                for (int r = 0; r < 16; ++r) {
                    int q = 4 * hi + (r & 3) + 8 * (r >> 2);
                    OB[q * 64 + dt * 32 + ml] = oacc[dt][r];
                }
        }
        __syncthreads();
        if (th == 0) {
#pragma unroll
            for (int dt = 0; dt < 2; ++dt)
#pragma unroll
                for (int r = 0; r < 16; ++r) {
                    int q = 4 * hi + (r & 3) + 8 * (r >> 2);
                    oacc[dt][r] += OB[q * 64 + dt * 32 + ml];
                }
        }
        __syncthreads();
        float* Lbuf = (float*)(smem + 32768);                  // [128 q]
        if (th == 1 && hi == 0) Lbuf[qq * 32 + ml] = lt;
        __syncthreads();
        if (th == 0 && hi == 0) Lbuf[qq * 32 + ml] += lt;
        __syncthreads();
        if (th == 0) {
            half_t* cslab = ctx + ((size_t)((b_ * 16 + sq) * 16 + h)) * 8192;
#pragma unroll
            for (int dt = 0; dt < 2; ++dt)
#pragma unroll
                for (int r = 0; r < 16; ++r) {
                    int qw = 4 * hi + (r & 3) + 8 * (r >> 2);
                    int q = qq * 32 + qw;
                    int d = dt * 32 + ml;
                    float linv = __builtin_amdgcn_rcpf(Lbuf[q]);
                    cslab[((d >> 3) * 128 + q) * 8 + (d & 7)] =
                        (half_t)(oacc[dt][r] * linv);
                }
        }
    }
    gridbar(bar, 2);

    // ========== phase 4: output projection (256 jobs on even blocks, sb0) ==========
    {
        bool active = (sb == 0) && ((bid & 1) == 0);
        gemm_tile_out(bid >> 1, t256, smem + (size_t)sb * 32768, active,
                      ctx, wt + (size_t)3 * 1048576, bo, out);
    }
}

extern "C" void kernel_launch(void* const* d_in, const int* in_sizes, int n_in,
                              void* d_out, int out_size, void* d_ws, size_t ws_size,
                              hipStream_t stream)
{
    const float* qx = (const float*)d_in[0];
    const float* kx = (const float*)d_in[1];
    const float* vx = (const float*)d_in[2];
    const float* Wq = (const float*)d_in[3];
    const float* bq = (const float*)d_in[4];
    const float* Wk = (const float*)d_in[5];
    const float* bk = (const float*)d_in[6];
    const float* Wv = (const float*)d_in[7];
    const float* bv = (const float*)d_in[8];
    const float* Wo = (const float*)d_in[9];
    const float* bo = (const float*)d_in[10];
    float* out = (float*)d_out;

    half_t* ws = (half_t*)d_ws;
    const size_t NT = (size_t)4096 * 1024;
    half_t* qxh = ws;                           // blocked A: qx fp16
    half_t* kxh = qxh + NT;
    half_t* vxh = kxh + NT;
    half_t* wt = vxh + NT;                      // blocked W^T x4
    half_t* qh = wt + (size_t)4 * 1048576;      // per-head blocked Q (pre-scaled)
    half_t* kh = qh + NT;                       // per-head blocked K
    half_t* vtr = kh + NT;                      // per-head blocked V^T
    half_t* ctx = vtr + NT;                     // blocked ctx
    unsigned* bar = (unsigned*)(ctx + NT);      // 3 x 64B barrier slots

    hipMemsetAsync((void*)bar, 0, 256, stream);
    fused<<<dim3(512), dim3(512), 0, stream>>>(
        qx, kx, vx, Wq, bq, Wk, bk, Wv, bv, Wo, bo, out,
        qxh, kxh, vxh, wt, qh, kh, vtr, ctx, bar);
}

// Round 7
// 544.690 us; speedup vs baseline: 1.1213x; 1.1213x over previous
//
#include <hip/hip_runtime.h>

typedef _Float16 half_t;
typedef _Float16 half8 __attribute__((ext_vector_type(8)));
typedef __fp16 fp16x2 __attribute__((ext_vector_type(2)));   // native type of cvt_pkrtz/fdot2
typedef float f32x16 __attribute__((ext_vector_type(16)));
typedef float f32x4v __attribute__((ext_vector_type(4)));
typedef unsigned uint2v __attribute__((ext_vector_type(2)));

#define MFMA32(A, B, C) __builtin_amdgcn_mfma_f32_32x32x16_f16(A, B, C, 0, 0, 0)

#if __has_builtin(__builtin_amdgcn_exp2f)
#define EXP2F(x) __builtin_amdgcn_exp2f(x)
#else
#define EXP2F(x) exp2f(x)
#endif

static constexpr int S = 2048;
static constexpr int D = 1024;
// log2(e)/8: folds the 1/sqrt(64) score scale and exp->exp2 change of base into Q
static constexpr float QSCALE = 0.18033688011112042f;

// R12 LESSON: hipLaunchCooperativeKernel + cg::grid.sync() was racy here.
// R13 LESSON: fusion passed but 530 us with ALL pipes ~5% busy -> the barrier
// spin was the sink: cnt+flag shared a cacheline (acquire-load storm starves
// the last atomicAdds; plain loads can also serve stale cross-XCD data until
// eviction). R14: barrier = one 256B-strided counter per phase, arrive =
// atomicAdd(+1), wait = poll atomicAdd(+0) (device-coherent RMW read, FIFO
// with the increments -> no starvation, no staleness) with s_sleep(16)
// backoff. Fences unchanged (R13 proved data propagation correct).
// Phase bodies verbatim from the verified pipeline (R11 attn).

// async global->LDS, 16B per lane; LDS dest = wave-uniform base + lane*16
__device__ __forceinline__ void gload_lds16(const void* g, void* l) {
    __builtin_amdgcn_global_load_lds(
        (const __attribute__((address_space(1))) unsigned int*)g,
        (__attribute__((address_space(3))) unsigned int*)l, 16, 0, 0);
}

// ---------------- grid barrier (one 256B-strided atomic counter per phase) ----------------
__device__ __forceinline__ void gridbar(unsigned* bar, int idx) {
    __syncthreads();                     // block done with phase
    if (threadIdx.x == 0) {
        __threadfence();                 // release: flush this block's writes
        unsigned* cnt = bar + idx * 64;  // 64 unsigneds = 256 B apart
        atomicAdd(cnt, 1u);              // device-scope arrive
        while (atomicAdd(cnt, 0u) < 512u)        // coherent RMW read, never stale
            __builtin_amdgcn_s_sleep(16);        // ~1k-cycle backoff
    }
    __syncthreads();                     // rest of block waits on lane 0
    __threadfence();                     // acquire: drop stale L1/L2 lines
}

// ---------------- 128x128 GEMM tile body (4-wave sub-block) ----------------
// t in 0..255 within the sub-block; sm = 32 KB LDS for this sub-block.
// All __syncthreads() are block-wide: both sub-blocks run identical trip
// counts, and inactive sub-blocks still execute every barrier.
__device__ __forceinline__ void gemm_tile_qkv(
    int job, int t, char* sm, bool active,
    const half_t* __restrict__ a0, const half_t* __restrict__ a1, const half_t* __restrict__ a2,
    const half_t* __restrict__ wt,
    const float* __restrict__ b0, const float* __restrict__ b1, const float* __restrict__ b2,
    half_t* __restrict__ qh, half_t* __restrict__ kh, half_t* __restrict__ vtb)
{
    half_t* As = (half_t*)sm;
    half_t* Bs = (half_t*)(sm + 16384);
    int z = job >> 8;
    int L = job & 255;
    const half_t* A = (z == 0) ? a0 : (z == 1) ? a1 : a2;
    const half_t* BT = wt + (size_t)z * 1048576;
    const float* bias = (z == 0) ? b0 : (z == 1) ? b1 : b2;
    int w = L >> 3;
    int mt = (L & 7) * 4 + (w & 3);
    int nt8 = w >> 2;
    int m0 = mt * 128, n0 = nt8 * 128;
    int lane = t & 63, wave = t >> 6;
    int ml = lane & 31, hi = lane >> 5;
    int wm = (wave & 1) * 64, wn = (wave >> 1) * 64;

    f32x16 acc00 = {}, acc01 = {}, acc10 = {}, acc11 = {};

    for (int kt = 0; kt < 16; ++kt) {
        __syncthreads();
        if (active) {
            const half_t* Aslab = A + ((size_t)(mt * 16 + kt)) * 8192;
            const half_t* Bslab = BT + ((size_t)(nt8 * 16 + kt)) * 8192;
#pragma unroll
            for (int j = 0; j < 4; ++j) {
                int s = wave * 4 + j;
                gload_lds16(Aslab + s * 512 + lane * 8, As + s * 512);
                gload_lds16(Bslab + s * 512 + lane * 8, Bs + s * 512);
            }
        }
        __syncthreads();
        if (active) {
#pragma unroll
            for (int ks = 0; ks < 4; ++ks) {
                int co = (2 * ks + hi) * 128;
                half8 af0 = *(const half8*)(As + (size_t)(co + wm + ml) * 8);
                half8 af1 = *(const half8*)(As + (size_t)(co + wm + 32 + ml) * 8);
                half8 bf0 = *(const half8*)(Bs + (size_t)(co + wn + ml) * 8);
                half8 bf1 = *(const half8*)(Bs + (size_t)(co + wn + 32 + ml) * 8);
                acc00 = MFMA32(af0, bf0, acc00);
                acc01 = MFMA32(af0, bf1, acc01);
                acc10 = MFMA32(af1, bf0, acc10);
                acc11 = MFMA32(af1, bf1, acc11);
            }
        }
    }

    // ---- epilogue: C tile -> swizzled LDS buf -> coalesced blocked global ----
    __syncthreads();
    half_t* buf = (half_t*)sm;
    if (active) {
#pragma unroll
        for (int nt = 0; nt < 2; ++nt) {
            int nl = wn + nt * 32 + ml;
            float bv = bias[n0 + nl];
            int hh = nl >> 6, c = (nl >> 3) & 7, j = nl & 7, dd = nl & 63;
#pragma unroll
            for (int mt2 = 0; mt2 < 2; ++mt2) {
                f32x16 av = (mt2 == 0) ? (nt == 0 ? acc00 : acc01) : (nt == 0 ? acc10 : acc11);
#pragma unroll
                for (int r = 0; r < 16; ++r) {
                    int rl = wm + mt2 * 32 + 4 * hi + (r & 3) + 8 * (r >> 2);
                    float v = av[r] + bv;
                    if (z == 0) v *= QSCALE;
                    if (z <= 1) {
                        buf[((rl * 2 + hh) * 8 + (c ^ (rl & 7))) * 8 + j] = (half_t)v;
                    } else {
                        int cc = rl >> 3, js = rl & 7;
                        buf[((dd * 2 + hh) * 16 + (cc ^ (dd & 7))) * 8 + js] = (half_t)v;
                    }
                }
            }
        }
    }
    __syncthreads();
    if (active) {
        int bq_ = m0 >> 11, skt = (m0 >> 7) & 15, h0 = n0 >> 6;
        half_t* dstm = (z == 0) ? qh : (z == 1) ? kh : vtb;
#pragma unroll
        for (int i = 0; i < 8; ++i) {
            int o = t + 256 * i;        // 2048 x 16B chunks
            int hh = o >> 10;
            half_t* gdst = dstm + ((size_t)(bq_ * 16 + h0 + hh)) * 131072 + (size_t)skt * 8192;
            half8 v8;
            int off;
            if (z <= 1) {
                int c = (o >> 7) & 7, r = o & 127;
                v8 = *(const half8*)(buf + (((r * 2 + hh) * 8 + (c ^ (r & 7))) * 8));
                off = (c * 128 + r) * 8;
            } else {
                int cc = (o >> 6) & 15, dd = o & 63;
                v8 = *(const half8*)(buf + (((dd * 2 + hh) * 16 + (cc ^ (dd & 7))) * 8));
                off = (cc * 64 + dd) * 8;
            }
            *(half8*)(gdst + off) = v8;
        }
    }
}

__device__ __forceinline__ void gemm_tile_out(
    int L, int t, char* sm, bool active,
    const half_t* __restrict__ A, const half_t* __restrict__ BT,
    const float* __restrict__ bias, float* __restrict__ out)
{
    half_t* As = (half_t*)sm;
    half_t* Bs = (half_t*)(sm + 16384);
    int w = L >> 3;
    int mt = (L & 7) * 4 + (w & 3);
    int nt8 = w >> 2;
    int m0 = mt * 128, n0 = nt8 * 128;
    int lane = t & 63, wave = t >> 6;
    int ml = lane & 31, hi = lane >> 5;
    int wm = (wave & 1) * 64, wn = (wave >> 1) * 64;

    f32x16 acc00 = {}, acc01 = {}, acc10 = {}, acc11 = {};

    for (int kt = 0; kt < 16; ++kt) {
        __syncthreads();
        if (active) {
            const half_t* Aslab = A + ((size_t)(mt * 16 + kt)) * 8192;
            const half_t* Bslab = BT + ((size_t)(nt8 * 16 + kt)) * 8192;
#pragma unroll
            for (int j = 0; j < 4; ++j) {
                int s = wave * 4 + j;
                gload_lds16(Aslab + s * 512 + lane * 8, As + s * 512);
                gload_lds16(Bslab + s * 512 + lane * 8, Bs + s * 512);
            }
        }
        __syncthreads();
        if (active) {
#pragma unroll
            for (int ks = 0; ks < 4; ++ks) {
                int co = (2 * ks + hi) * 128;
                half8 af0 = *(const half8*)(As + (size_t)(co + wm + ml) * 8);
                half8 af1 = *(const half8*)(As + (size_t)(co + wm + 32 + ml) * 8);
                half8 bf0 = *(const half8*)(Bs + (size_t)(co + wn + ml) * 8);
                half8 bf1 = *(const half8*)(Bs + (size_t)(co + wn + 32 + ml) * 8);
                acc00 = MFMA32(af0, bf0, acc00);
                acc01 = MFMA32(af0, bf1, acc01);
                acc10 = MFMA32(af1, bf0, acc10);
                acc11 = MFMA32(af1, bf1, acc11);
            }
        }
    }

    if (active) {
#pragma unroll
        for (int nt = 0; nt < 2; ++nt) {
            int n = n0 + wn + nt * 32 + ml;
            float bv = bias[n];
#pragma unroll
            for (int mt2 = 0; mt2 < 2; ++mt2) {
                f32x16 av = (mt2 == 0) ? (nt == 0 ? acc00 : acc01) : (nt == 0 ? acc10 : acc11);
                int rbase = m0 + wm + mt2 * 32 + 4 * hi;
#pragma unroll
                for (int r = 0; r < 16; ++r) {
                    int row = rbase + (r & 3) + 8 * (r >> 2);
                    out[(size_t)row * D + n] = av[r] + bv;
                }
            }
        }
    }
}

// ---------------- the fused kernel (plain launch, atomic-counter grid barrier) ----------------
__global__ __launch_bounds__(512, 4) void fused(
    const float* __restrict__ qx, const float* __restrict__ kx, const float* __restrict__ vx,
    const float* __restrict__ Wq, const float* __restrict__ bq,
    const float* __restrict__ Wk, const float* __restrict__ bk,
    const float* __restrict__ Wv, const float* __restrict__ bv,
    const float* __restrict__ Wo, const float* __restrict__ bo,
    float* __restrict__ out,
    half_t* __restrict__ qxh, half_t* __restrict__ kxh, half_t* __restrict__ vxh,
    half_t* __restrict__ wt, half_t* __restrict__ qh, half_t* __restrict__ kh,
    half_t* __restrict__ vtr, half_t* __restrict__ ctx, unsigned* __restrict__ bar)
{
    __shared__ char smem[65536];
    int bid = blockIdx.x;
    int t = threadIdx.x;
    int sb = t >> 8, t256 = t & 255;

    // ========== phase 1: fp32 -> fp16 blocked conversion (2048 jobs) ==========
    for (int job = bid; job < 2048; job += 512) {
        __syncthreads();   // protect LDS from previous job's readers
        int y = job >> 9, x = job & 511;
        if (y < 3) {
            float (*tile)[65] = (float(*)[65])smem;
            const float* src = (y == 0) ? qx : (y == 1) ? kx : vx;
            half_t* dst = (y == 0) ? qxh : (y == 1) ? kxh : vxh;
            int mt = x >> 4, kt = x & 15;
            const float* sbase = src + (size_t)(mt * 128) * D + kt * 64;
            int rr = t >> 4, col = (t & 15) * 4;
#pragma unroll
            for (int p = 0; p < 4; ++p) {
                int row = rr + p * 32;
                f32x4v v = *(const f32x4v*)(sbase + (size_t)row * D + col);
                tile[row][col] = v[0]; tile[row][col + 1] = v[1];
                tile[row][col + 2] = v[2]; tile[row][col + 3] = v[3];
            }
            __syncthreads();
            int c = t >> 6, r0 = t & 63;
            half_t* dbase = dst + ((size_t)(mt * 16 + kt)) * 8192;
#pragma unroll
            for (int i = 0; i < 2; ++i) {
                int row = r0 + 64 * i;
                half8 h;
#pragma unroll
                for (int j = 0; j < 8; ++j) h[j] = (half_t)tile[row][c * 8 + j];
                *(half8*)(dbase + ((size_t)c * 128 + row) * 8) = h;
            }
        } else {
            float (*tile)[129] = (float(*)[129])smem;
            int w = x >> 7;
            const float* W = (w == 0) ? Wq : (w == 1) ? Wk : (w == 2) ? Wv : Wo;
            int idx = x & 127;
            int nt = idx >> 4, kt = idx & 15;
            const float* sbase = W + (size_t)(kt * 64) * D + nt * 128;
            int kr = t >> 5, col = (t & 31) * 4;
#pragma unroll
            for (int p = 0; p < 4; ++p) {
                int k = kr + p * 16;
                f32x4v v = *(const f32x4v*)(sbase + (size_t)k * D + col);
                tile[k][col] = v[0]; tile[k][col + 1] = v[1];
                tile[k][col + 2] = v[2]; tile[k][col + 3] = v[3];
            }
            __syncthreads();
            int c = t >> 6, r0 = t & 63;
            half_t* dbase = wt + (size_t)w * 1048576 + ((size_t)(nt * 16 + kt)) * 8192;
#pragma unroll
            for (int i = 0; i < 2; ++i) {
                int n = r0 + 64 * i;
                half8 h;
#pragma unroll
                for (int j = 0; j < 8; ++j) h[j] = (half_t)tile[c * 8 + j][n];
                *(half8*)(dbase + ((size_t)c * 128 + n) * 8) = h;
            }
        }
    }
    gridbar(bar, 0);

    // ========== phase 2: QKV projection GEMMs (768 jobs, 2 sub-blocks/block) ==========
    {
        int job; bool active;
        if (sb == 0) { job = bid; active = true; }                       // z = 0,1
        else { job = 512 + (bid >> 1); active = ((bid & 1) == 0); }      // z = 2 on even blocks
        gemm_tile_qkv(active ? job : 0, t256, smem + (size_t)sb * 32768, active,
                      qxh, kxh, vxh, wt, bq, bk, bv, qh, kh, vtr);
    }
    gridbar(bar, 1);

    // ========== phase 3: fused attention (512 jobs, 1 per block; R11 body) ==========
    {
        int L = bid;
        int slot = L >> 3;
        int bh = (L & 7) + 8 * (slot >> 4);
        int sq = slot & 15;
        int b_ = bh >> 4, h = bh & 15;

        int lane = t & 63, wave = t >> 6;
        int ml = lane & 31, hi = lane >> 5;
        int qq = wave & 3, th = wave >> 2;
        const half_t* qslab = qh + (size_t)bh * 131072 + (size_t)sq * 8192;
        const half_t* khead = kh + (size_t)bh * 131072;
        const half_t* vhead = vtr + (size_t)bh * 131072;

        // stage Q into Ks(1) region and K/V tile 0 into buf0 (single barrier)
        {
            half_t* QB = (half_t*)(smem + 32768);
            half_t* K0 = (half_t*)(smem);
            half_t* V0 = (half_t*)(smem + 16384);
#pragma unroll
            for (int j = 0; j < 2; ++j) {
                int s = wave * 2 + j;
                gload_lds16(qslab + s * 512 + lane * 8, QB + s * 512);
                gload_lds16(khead + s * 512 + lane * 8, K0 + s * 512);
                gload_lds16(vhead + s * 512 + lane * 8, V0 + s * 512);
            }
        }
        __syncthreads();
        half8 qf[4];
        {
            half_t* QB = (half_t*)(smem + 32768);
#pragma unroll
            for (int ks = 0; ks < 4; ++ks)
                qf[ks] = *(const half8*)(QB + ((size_t)((2 * ks + hi) * 128 + qq * 32 + ml)) * 8);
        }
        __syncthreads();   // all qf reads complete before buf1 (= QB region) is restaged

        f32x16 oacc[2] = {};
        float lsumA = 0.0f, lsumB = 0.0f;
        fp16x2 one2; one2.x = (__fp16)1.0f; one2.y = (__fp16)1.0f;
        const f32x16 sinit = {-10.0f, -10.0f, -10.0f, -10.0f, -10.0f, -10.0f, -10.0f, -10.0f,
                              -10.0f, -10.0f, -10.0f, -10.0f, -10.0f, -10.0f, -10.0f, -10.0f};

        int t0 = th * 2, t1 = th * 2 + 1;

        for (int it = 0; it < 16; ++it) {
            int bb = it & 1;
            if (it < 15) {   // prefetch next tile into the other buffer (overlaps compute)
                const half_t* kslab = khead + (size_t)(it + 1) * 8192;
                const half_t* vslab = vhead + (size_t)(it + 1) * 8192;
                half_t* Kd = (half_t*)(smem + (bb ^ 1) * 32768);
                half_t* Vd = (half_t*)(smem + 16384 + (bb ^ 1) * 32768);
#pragma unroll
                for (int j = 0; j < 2; ++j) {
                    int s = wave * 2 + j;
                    gload_lds16(kslab + s * 512 + lane * 8, Kd + s * 512);
                    gload_lds16(vslab + s * 512 + lane * 8, Vd + s * 512);
                }
            }
            half_t* Ks  = (half_t*)(smem + bb * 32768);
            half_t* VTs = (half_t*)(smem + 16384 + bb * 32768);

            // ---- QK for both k-subtiles, interleaved ----
            f32x16 sv0 = sinit, sv1 = sinit;
            __builtin_amdgcn_s_setprio(1);
#pragma unroll
            for (int ks = 0; ks < 4; ++ks) {
                half8 kf0 = *(const half8*)(Ks + ((size_t)((2 * ks + hi) * 128 + t0 * 32 + ml)) * 8);
                half8 kf1 = *(const half8*)(Ks + ((size_t)((2 * ks + hi) * 128 + t1 * 32 + ml)) * 8);
                sv0 = MFMA32(kf0, qf[ks], sv0);
                sv1 = MFMA32(kf1, qf[ks], sv1);
            }
            __builtin_amdgcn_s_setprio(0);

            // ---- SM0 ----
            unsigned pkv0[8];
            {
                float lsA = lsumA;
#pragma unroll
                for (int j = 0; j < 8; ++j) {
                    float pa = EXP2F(sv0[2 * j]);
                    float pb = EXP2F(sv0[2 * j + 1]);
#if __has_builtin(__builtin_amdgcn_cvt_pkrtz)
                    fp16x2 h2 = __builtin_amdgcn_cvt_pkrtz(pa, pb);
#else
                    fp16x2 h2; h2.x = (__fp16)pa; h2.y = (__fp16)pb;
#endif
                    pkv0[j] = __builtin_bit_cast(unsigned, h2);
#if __has_builtin(__builtin_amdgcn_fdot2)
                    lsA = __builtin_amdgcn_fdot2(h2, one2, lsA, false);
#else
                    lsA += pa + pb;
#endif
                }
                lsumA = lsA;
            }

            // ---- PV0 ----
#pragma unroll
            for (int kp = 0; kp < 2; ++kp) {
                union { unsigned u[4]; half8 h; } fr;
#if __has_builtin(__builtin_amdgcn_permlane32_swap)
                uint2v w0 = __builtin_amdgcn_permlane32_swap(pkv0[4 * kp + 0], pkv0[4 * kp + 2], false, false);
                uint2v w1 = __builtin_amdgcn_permlane32_swap(pkv0[4 * kp + 1], pkv0[4 * kp + 3], false, false);
                fr.u[0] = w0.x; fr.u[1] = w1.x; fr.u[2] = w0.y; fr.u[3] = w1.y;
#else
                unsigned e0 = pkv0[4 * kp + 0], e1 = pkv0[4 * kp + 1];
                unsigned o0 = pkv0[4 * kp + 2], o1 = pkv0[4 * kp + 3];
                unsigned s0u = hi ? e0 : o0, s1u = hi ? e1 : o1;
                unsigned k0u = hi ? o0 : e0, k1u = hi ? o1 : e1;
                unsigned r0 = __shfl_xor(s0u, 32, 64);
                unsigned r1 = __shfl_xor(s1u, 32, 64);
                fr.u[0] = hi ? r0 : k0u; fr.u[1] = hi ? r1 : k1u;
                fr.u[2] = hi ? k0u : r0; fr.u[3] = hi ? k1u : r1;
#endif
                __builtin_amdgcn_s_setprio(1);
#pragma unroll
                for (int dt = 0; dt < 2; ++dt) {
                    half8 vf = *(const half8*)(VTs + ((size_t)((4 * t0 + 2 * kp + hi) * 64 + dt * 32 + ml)) * 8);
                    oacc[dt] = MFMA32(fr.h, vf, oacc[dt]);
                }
                __builtin_amdgcn_s_setprio(0);
            }

            // ---- SM1 ----
            unsigned pkv1[8];
            {
                float lsB = lsumB;
#pragma unroll
                for (int j = 0; j < 8; ++j) {
                    float pa = EXP2F(sv1[2 * j]);
                    float pb = EXP2F(sv1[2 * j + 1]);
#if __has_builtin(__builtin_amdgcn_cvt_pkrtz)
                    fp16x2 h2 = __builtin_amdgcn_cvt_pkrtz(pa, pb);
#else
                    fp16x2 h2; h2.x = (__fp16)pa; h2.y = (__fp16)pb;
#endif
                    pkv1[j] = __builtin_bit_cast(unsigned, h2);
#if __has_builtin(__builtin_amdgcn_fdot2)
                    lsB = __builtin_amdgcn_fdot2(h2, one2, lsB, false);
#else
                    lsB += pa + pb;
#endif
                }
                lsumB = lsB;
            }

            // ---- PV1 ----
#pragma unroll
            for (int kp = 0; kp < 2; ++kp) {
                union { unsigned u[4]; half8 h; } fr;
#if __has_builtin(__builtin_amdgcn_permlane32_swap)
                uint2v w0 = __builtin_amdgcn_permlane32_swap(pkv1[4 * kp + 0], pkv1[4 * kp + 2], false, false);
                uint2v w1 = __builtin_amdgcn_permlane32_swap(pkv1[4 * kp + 1], pkv1[4 * kp + 3], false, false);
                fr.u[0] = w0.x; fr.u[1] = w1.x; fr.u[2] = w0.y; fr.u[3] = w1.y;
#else
                unsigned e0 = pkv1[4 * kp + 0], e1 = pkv1[4 * kp + 1];
                unsigned o0 = pkv1[4 * kp + 2], o1 = pkv1[4 * kp + 3];
                unsigned s0u = hi ? e0 : o0, s1u = hi ? e1 : o1;
                unsigned k0u = hi ? o0 : e0, k1u = hi ? o1 : e1;
                unsigned r0 = __shfl_xor(s0u, 32, 64);
                unsigned r1 = __shfl_xor(s1u, 32, 64);
                fr.u[0] = hi ? r0 : k0u; fr.u[1] = hi ? r1 : k1u;
                fr.u[2] = hi ? k0u : r0; fr.u[3] = hi ? k1u : r1;
#endif
                __builtin_amdgcn_s_setprio(1);
#pragma unroll
                for (int dt = 0; dt < 2; ++dt) {
                    half8 vf = *(const half8*)(VTs + ((size_t)((4 * t1 + 2 * kp + hi) * 64 + dt * 32 + ml)) * 8);
                    oacc[dt] = MFMA32(fr.h, vf, oacc[dt]);
                }
                __builtin_amdgcn_s_setprio(0);
            }

            __syncthreads();   // drains the it+1 prefetch
        }

        // ---- epilogue: combine th partials, normalize, store ----
        float lsum = lsumA + lsumB;
        float lt = lsum + __shfl_xor(lsum, 32, 64);

        float* OB = (float*)(smem + (size_t)qq * 8192);
        if (th == 1) {
#pragma unroll
            for (int dt = 0; dt < 2; ++dt)
#pragma unroll
                for (int r = 0; r < 16; ++r) {
                    int q = 4 * hi + (r & 3) + 8 * (r >> 2);
                    OB[q * 64 + dt * 32 + ml] = oacc[dt][r];
                }
        }
        __syncthreads();
        if (th == 0) {
#pragma unroll
            for (int dt = 0; dt < 2; ++dt)
#pragma unroll
                for (int r = 0; r < 16; ++r) {
                    int q = 4 * hi + (r & 3) + 8 * (r >> 2);
                    oacc[dt][r] += OB[q * 64 + dt * 32 + ml];
                }
        }
        __syncthreads();
        float* Lbuf = (float*)(smem + 32768);                  // [128 q]
        if (th == 1 && hi == 0) Lbuf[qq * 32 + ml] = lt;
        __syncthreads();
        if (th == 0 && hi == 0) Lbuf[qq * 32 + ml] += lt;
        __syncthreads();
        if (th == 0) {
            half_t* cslab = ctx + ((size_t)((b_ * 16 + sq) * 16 + h)) * 8192;
#pragma unroll
            for (int dt = 0; dt < 2; ++dt)
#pragma unroll
                for (int r = 0; r < 16; ++r) {
                    int qw = 4 * hi + (r & 3) + 8 * (r >> 2);
                    int q = qq * 32 + qw;
                    int d = dt * 32 + ml;
                    float linv = __builtin_amdgcn_rcpf(Lbuf[q]);
                    cslab[((d >> 3) * 128 + q) * 8 + (d & 7)] =
                        (half_t)(oacc[dt][r] * linv);
                }
        }
    }
    gridbar(bar, 2);

    // ========== phase 4: output projection (256 jobs on even blocks, sb0) ==========
    {
        bool active = (sb == 0) && ((bid & 1) == 0);
        gemm_tile_out(bid >> 1, t256, smem + (size_t)sb * 32768, active,
                      ctx, wt + (size_t)3 * 1048576, bo, out);
    }
}

extern "C" void kernel_launch(void* const* d_in, const int* in_sizes, int n_in,
                              void* d_out, int out_size, void* d_ws, size_t ws_size,
                              hipStream_t stream)
{
    const float* qx = (const float*)d_in[0];
    const float* kx = (const float*)d_in[1];
    const float* vx = (const float*)d_in[2];
    const float* Wq = (const float*)d_in[3];
    const float* bq = (const float*)d_in[4];
    const float* Wk = (const float*)d_in[5];
    const float* bk = (const float*)d_in[6];
    const float* Wv = (const float*)d_in[7];
    const float* bv = (const float*)d_in[8];
    const float* Wo = (const float*)d_in[9];
    const float* bo = (const float*)d_in[10];
    float* out = (float*)d_out;

    half_t* ws = (half_t*)d_ws;
    const size_t NT = (size_t)4096 * 1024;
    half_t* qxh = ws;                           // blocked A: qx fp16
    half_t* kxh = qxh + NT;
    half_t* vxh = kxh + NT;
    half_t* wt = vxh + NT;                      // blocked W^T x4
    half_t* qh = wt + (size_t)4 * 1048576;      // per-head blocked Q (pre-scaled)
    half_t* kh = qh + NT;                       // per-head blocked K
    half_t* vtr = kh + NT;                      // per-head blocked V^T
    half_t* ctx = vtr + NT;                     // blocked ctx
    unsigned* bar = (unsigned*)(ctx + NT);      // 3 x 256B barrier counter slots

    hipMemsetAsync((void*)bar, 0, 1024, stream);
    fused<<<dim3(512), dim3(512), 0, stream>>>(
        qx, kx, vx, Wq, bq, Wk, bk, Wv, bv, Wo, bo, out,
        qxh, kxh, vxh, wt, qh, kh, vtr, ctx, bar);
}

// Round 8
// 206.555 us; speedup vs baseline: 2.9568x; 2.6370x over previous
//
#include <hip/hip_runtime.h>

typedef _Float16 half_t;
typedef _Float16 half8 __attribute__((ext_vector_type(8)));
typedef __fp16 fp16x2 __attribute__((ext_vector_type(2)));   // native type of cvt_pkrtz/fdot2
typedef float f32x16 __attribute__((ext_vector_type(16)));
typedef float f32x4v __attribute__((ext_vector_type(4)));
typedef unsigned uint2v __attribute__((ext_vector_type(2)));

#define MFMA32(A, B, C) __builtin_amdgcn_mfma_f32_32x32x16_f16(A, B, C, 0, 0, 0)

#if __has_builtin(__builtin_amdgcn_exp2f)
#define EXP2F(x) __builtin_amdgcn_exp2f(x)
#else
#define EXP2F(x) exp2f(x)
#endif

static constexpr int S = 2048;
static constexpr int D = 1024;
// log2(e)/8: folds the 1/sqrt(64) score scale and exp->exp2 change of base into Q
static constexpr float QSCALE = 0.18033688011112042f;

// Blocked "slab" layout: slabs of 128 rows x 64 cols = 8192 halves
// [c(8)][r(128)][j(8)], byte-identical to the LDS tile -> global_load_lds reads
// contiguous 1 KB segments.
// R8: 512 thr / 8 waves attn. R9 LESSON: watch WRITE_SIZE for spill whenever
// register state grows (cap is 128 VGPR at (512,4)).
// R10: -10 bias folded into QK MFMA C-init; dual fdot2 chains. attn 44.8 us.
// R11: QK(sv0,sv1) up front, SM0->PV0->SM1->PV1. attn 44.4 us. Neutral vs R10
// -> compiler already schedules across phases; kept (it is the measured best).
// R12-R14 LESSON (fusion abandoned): single-kernel fusion with grid barriers
// (cooperative OR hand-rolled atomic) ran 470-530 us with ALL pipes ~6% busy
// despite verbatim phase bodies and full co-residency -- lockstep phase
// execution idles ~90% in a way three sync designs couldn't fix. Reverted.
// R15 (this round): gemm_out was the only 256-block dispatch (1 block/CU,
// 4 waves -- latency-exposed in the 2-barrier lockstep). Split to 128x64
// tiles -> 512 blocks, 2 blocks/CU, 8 waves/CU; B staging halves to 8 gloads.

// async global->LDS, 16B per lane; LDS dest = wave-uniform base + lane*16
__device__ __forceinline__ void gload_lds16(const void* g, void* l) {
    __builtin_amdgcn_global_load_lds(
        (const __attribute__((address_space(1))) unsigned int*)g,
        (__attribute__((address_space(3))) unsigned int*)l, 16, 0, 0);
}

// ---------------- fused convert kernel ----------------
// y in 0..2: qx/kx/vx fp32 -> fp16 blocked slabs (512 x-blocks each)
// y == 3:    Wq/Wk/Wv/Wo fp32 -> fp16 blocked W^T slabs (4 x 128 x-blocks)
__global__ __launch_bounds__(256) void cvtw(
    const float* __restrict__ x0, const float* __restrict__ x1, const float* __restrict__ x2,
    const float* __restrict__ w0, const float* __restrict__ w1,
    const float* __restrict__ w2, const float* __restrict__ w3,
    half_t* __restrict__ o0, half_t* __restrict__ o1, half_t* __restrict__ o2,
    half_t* __restrict__ wt)
{
    __shared__ char sm[33280];
    int y = blockIdx.y;
    int t = threadIdx.x;
    if (y < 3) {
        float (*tile)[65] = (float(*)[65])sm;
        const float* src = (y == 0) ? x0 : (y == 1) ? x1 : x2;
        half_t* dst = (y == 0) ? o0 : (y == 1) ? o1 : o2;
        int mt = blockIdx.x >> 4, kt = blockIdx.x & 15;
        const float* sbase = src + (size_t)(mt * 128) * D + kt * 64;
        int rr = t >> 4, col = (t & 15) * 4;
#pragma unroll
        for (int p = 0; p < 8; ++p) {
            int row = rr + p * 16;
            f32x4v v = *(const f32x4v*)(sbase + (size_t)row * D + col);
            tile[row][col] = v[0]; tile[row][col + 1] = v[1];
            tile[row][col + 2] = v[2]; tile[row][col + 3] = v[3];
        }
        __syncthreads();
        int c = t >> 5, r0 = t & 31;
        half_t* dbase = dst + ((size_t)(mt * 16 + kt)) * 8192;
#pragma unroll
        for (int i = 0; i < 4; ++i) {
            int row = r0 + 32 * i;
            half8 h;
#pragma unroll
            for (int j = 0; j < 8; ++j) h[j] = (half_t)tile[row][c * 8 + j];
            *(half8*)(dbase + ((size_t)c * 128 + row) * 8) = h;
        }
    } else {
        float (*tile)[129] = (float(*)[129])sm;
        int w = blockIdx.x >> 7;
        const float* W = (w == 0) ? w0 : (w == 1) ? w1 : (w == 2) ? w2 : w3;
        int idx = blockIdx.x & 127;
        int nt = idx >> 4, kt = idx & 15;
        const float* sbase = W + (size_t)(kt * 64) * D + nt * 128;
        int kr = t >> 5, col = (t & 31) * 4;
#pragma unroll
        for (int p = 0; p < 8; ++p) {
            int k = kr + p * 8;
            f32x4v v = *(const f32x4v*)(sbase + (size_t)k * D + col);
            tile[k][col] = v[0]; tile[k][col + 1] = v[1];
            tile[k][col + 2] = v[2]; tile[k][col + 3] = v[3];
        }
        __syncthreads();
        int c = t >> 5, r0 = t & 31;
        half_t* dbase = wt + (size_t)w * 1048576 + ((size_t)(nt * 16 + kt)) * 8192;
#pragma unroll
        for (int i = 0; i < 4; ++i) {
            int n = r0 + 32 * i;
            half8 h;
#pragma unroll
            for (int j = 0; j < 8; ++j) h[j] = (half_t)tile[c * 8 + j][n];
            *(half8*)(dbase + ((size_t)c * 128 + n) * 8) = h;
        }
    }
}

// ---------------- fused QKV projection GEMM ----------------
// XCD swizzle: xcd = L&7 owns mt in {4*xcd .. 4*xcd+3}; per-XCD L2 footprint
// = 4 A-slabs (1 MB) + full B (2 MB) = 3 MB < 4 MiB.
__global__ __launch_bounds__(256, 4) void gemm_qkv(
    const half_t* __restrict__ a0, const half_t* __restrict__ a1, const half_t* __restrict__ a2,
    const half_t* __restrict__ wt,
    const float* __restrict__ b0, const float* __restrict__ b1, const float* __restrict__ b2,
    half_t* __restrict__ qh, half_t* __restrict__ kh, half_t* __restrict__ vt)
{
    __shared__ char smem[32768];
    half_t* As = (half_t*)smem;
    half_t* Bs = (half_t*)(smem + 16384);
    int z = blockIdx.z;
    const half_t* A = (z == 0) ? a0 : (z == 1) ? a1 : a2;
    const half_t* BT = wt + (size_t)z * 1048576;
    const float* bias = (z == 0) ? b0 : (z == 1) ? b1 : b2;
    int L = blockIdx.x;
    int w = L >> 3;
    int mt = (L & 7) * 4 + (w & 3);
    int nt8 = w >> 2;
    int m0 = mt * 128, n0 = nt8 * 128;
    int tid = threadIdx.x, lane = tid & 63, wave = tid >> 6;
    int ml = lane & 31, hi = lane >> 5;
    int wm = (wave & 1) * 64, wn = (wave >> 1) * 64;

    f32x16 acc00 = {}, acc01 = {}, acc10 = {}, acc11 = {};

    for (int kt = 0; kt < 16; ++kt) {
        __syncthreads();
        const half_t* Aslab = A + ((size_t)(mt * 16 + kt)) * 8192;
        const half_t* Bslab = BT + ((size_t)(nt8 * 16 + kt)) * 8192;
#pragma unroll
        for (int j = 0; j < 4; ++j) {
            int s = wave * 4 + j;
            gload_lds16(Aslab + s * 512 + lane * 8, As + s * 512);
            gload_lds16(Bslab + s * 512 + lane * 8, Bs + s * 512);
        }
        __syncthreads();
#pragma unroll
        for (int ks = 0; ks < 4; ++ks) {
            int co = (2 * ks + hi) * 128;
            half8 af0 = *(const half8*)(As + (size_t)(co + wm + ml) * 8);
            half8 af1 = *(const half8*)(As + (size_t)(co + wm + 32 + ml) * 8);
            half8 bf0 = *(const half8*)(Bs + (size_t)(co + wn + ml) * 8);
            half8 bf1 = *(const half8*)(Bs + (size_t)(co + wn + 32 + ml) * 8);
            acc00 = MFMA32(af0, bf0, acc00);
            acc01 = MFMA32(af0, bf1, acc01);
            acc10 = MFMA32(af1, bf0, acc10);
            acc11 = MFMA32(af1, bf1, acc11);
        }
    }

    // ---- epilogue: C tile -> swizzled LDS buf -> coalesced blocked global ----
    __syncthreads();
    half_t* buf = (half_t*)smem;
#pragma unroll
    for (int nt = 0; nt < 2; ++nt) {
        int nl = wn + nt * 32 + ml;
        float bv = bias[n0 + nl];
        int hh = nl >> 6, c = (nl >> 3) & 7, j = nl & 7, dd = nl & 63;
#pragma unroll
        for (int mt2 = 0; mt2 < 2; ++mt2) {
            f32x16 av = (mt2 == 0) ? (nt == 0 ? acc00 : acc01) : (nt == 0 ? acc10 : acc11);
#pragma unroll
            for (int r = 0; r < 16; ++r) {
                int rl = wm + mt2 * 32 + 4 * hi + (r & 3) + 8 * (r >> 2);
                float v = av[r] + bv;
                if (z == 0) v *= QSCALE;
                if (z <= 1) {
                    buf[((rl * 2 + hh) * 8 + (c ^ (rl & 7))) * 8 + j] = (half_t)v;
                } else {
                    int cc = rl >> 3, js = rl & 7;
                    buf[((dd * 2 + hh) * 16 + (cc ^ (dd & 7))) * 8 + js] = (half_t)v;
                }
            }
        }
    }
    __syncthreads();
    int bq_ = m0 >> 11, skt = (m0 >> 7) & 15, h0 = n0 >> 6;
    half_t* dstm = (z == 0) ? qh : (z == 1) ? kh : vt;
#pragma unroll
    for (int i = 0; i < 8; ++i) {
        int o = tid + 256 * i;        // 2048 x 16B chunks
        int hh = o >> 10;
        half_t* gdst = dstm + ((size_t)(bq_ * 16 + h0 + hh)) * 131072 + (size_t)skt * 8192;
        half8 v8;
        int off;
        if (z <= 1) {
            int c = (o >> 7) & 7, r = o & 127;
            v8 = *(const half8*)(buf + (((r * 2 + hh) * 8 + (c ^ (r & 7))) * 8));
            off = (c * 128 + r) * 8;
        } else {
            int cc = (o >> 6) & 15, dd = o & 63;
            v8 = *(const half8*)(buf + (((dd * 2 + hh) * 16 + (cc ^ (dd & 7))) * 8));
            off = (cc * 64 + dd) * 8;
        }
        *(half8*)(gdst + off) = v8;
    }
}

// ---------------- output projection GEMM (fp32 out, row-major) ----------------
// R15: 128x64 tiles, 512 blocks (2/CU, 8 waves/CU vs old 256-block 4 waves/CU).
// Per wave: 64m x 32n output = 2 accumulators. B-tile = half a 128-n slab.
__global__ __launch_bounds__(256, 4) void gemm_out(
    const half_t* __restrict__ A, const half_t* __restrict__ BT,
    const float* __restrict__ bias, float* __restrict__ out)
{
    __shared__ char smem[24576];
    half_t* As = (half_t*)smem;                  // 16 KB: [c(8)][r(128)][j(8)]
    half_t* Bs = (half_t*)(smem + 16384);        // 8 KB:  [c(8)][n(64)][j(8)]
    int L = blockIdx.x;
    int w = L >> 3;
    int mt = (L & 7) * 4 + (w & 3);              // 0..31
    int nt64 = w >> 2;                           // 0..15
    int ntS = nt64 >> 1, nh = nt64 & 1;          // slab index, half index
    int m0 = mt * 128, n0 = nt64 * 64;
    int tid = threadIdx.x, lane = tid & 63, wave = tid >> 6;
    int ml = lane & 31, hi = lane >> 5;
    int wm = (wave & 1) * 64, wn = (wave >> 1) * 32;

    f32x16 acc0 = {}, acc1 = {};

    for (int kt = 0; kt < 16; ++kt) {
        __syncthreads();
        const half_t* Aslab = A + ((size_t)(mt * 16 + kt)) * 8192;
        const half_t* Bslab = BT + ((size_t)(ntS * 16 + kt)) * 8192;
#pragma unroll
        for (int j = 0; j < 4; ++j) {
            int s = wave * 4 + j;
            gload_lds16(Aslab + s * 512 + lane * 8, As + s * 512);
        }
#pragma unroll
        for (int j = 0; j < 2; ++j) {
            int s2 = wave * 2 + j;
            gload_lds16(Bslab + ((size_t)s2 * 128 + nh * 64) * 8 + lane * 8, Bs + s2 * 512);
        }
        __syncthreads();
#pragma unroll
        for (int ks = 0; ks < 4; ++ks) {
            int co = 2 * ks + hi;
            half8 af0 = *(const half8*)(As + (size_t)(co * 128 + wm + ml) * 8);
            half8 af1 = *(const half8*)(As + (size_t)(co * 128 + wm + 32 + ml) * 8);
            half8 bf  = *(const half8*)(Bs + (size_t)(co * 64 + wn + ml) * 8);
            acc0 = MFMA32(af0, bf, acc0);
            acc1 = MFMA32(af1, bf, acc1);
        }
    }

    int n = n0 + wn + ml;
    float bv = bias[n];
#pragma unroll
    for (int mt2 = 0; mt2 < 2; ++mt2) {
        f32x16 av = (mt2 == 0) ? acc0 : acc1;
        int rbase = m0 + wm + mt2 * 32 + 4 * hi;
#pragma unroll
        for (int r = 0; r < 16; ++r) {
            int row = rbase + (r & 3) + 8 * (r >> 2);
            out[(size_t)row * D + n] = av[r] + bv;
        }
    }
}

// ---------------- fused attention, register-resident P, double-buffered K/V ----------------
// 64 KB LDS: buf b = { Ks at b*32K, VTs at 16K+b*32K }. Q staged once via Ks(1).
// R8 shape: 512 threads / 8 waves, wave -> (qq = wave&3, th = wave>>2).
// R11: QK(sv0,sv1 interleaved) then SM0 -> PV0 -> SM1 -> PV1; disjoint lsum chains.
__global__ __launch_bounds__(512, 4) void attn(
    const half_t* __restrict__ qh, const half_t* __restrict__ kh,
    const half_t* __restrict__ vt, half_t* __restrict__ ctx)
{
    __shared__ char smem[65536];

    // XCD swizzle: all 16 sq-blocks of one (b,h) land on one XCD (bh % 8)
    int L = blockIdx.x;
    int slot = L >> 3;
    int bh = (L & 7) + 8 * (slot >> 4);
    int sq = slot & 15;
    int b_ = bh >> 4, h = bh & 15;

    int tid = threadIdx.x, lane = tid & 63, wave = tid >> 6;
    int ml = lane & 31, hi = lane >> 5;
    int qq = wave & 3, th = wave >> 2;
    const half_t* qslab = qh + (size_t)bh * 131072 + (size_t)sq * 8192;
    const half_t* khead = kh + (size_t)bh * 131072;
    const half_t* vhead = vt + (size_t)bh * 131072;

    // stage Q into Ks(1) region and K/V tile 0 into buf0 (single barrier)
    {
        half_t* QB = (half_t*)(smem + 32768);
        half_t* K0 = (half_t*)(smem);
        half_t* V0 = (half_t*)(smem + 16384);
#pragma unroll
        for (int j = 0; j < 2; ++j) {
            int s = wave * 2 + j;
            gload_lds16(qslab + s * 512 + lane * 8, QB + s * 512);
            gload_lds16(khead + s * 512 + lane * 8, K0 + s * 512);
            gload_lds16(vhead + s * 512 + lane * 8, V0 + s * 512);
        }
    }
    __syncthreads();
    half8 qf[4];
    {
        half_t* QB = (half_t*)(smem + 32768);
#pragma unroll
        for (int ks = 0; ks < 4; ++ks)
            qf[ks] = *(const half8*)(QB + ((size_t)((2 * ks + hi) * 128 + qq * 32 + ml)) * 8);
    }
    __syncthreads();   // all qf reads complete before buf1 (= QB region) is restaged

    f32x16 oacc[2] = {};
    float lsumA = 0.0f, lsumB = 0.0f;
    fp16x2 one2; one2.x = (__fp16)1.0f; one2.y = (__fp16)1.0f;
    const f32x16 sinit = {-10.0f, -10.0f, -10.0f, -10.0f, -10.0f, -10.0f, -10.0f, -10.0f,
                          -10.0f, -10.0f, -10.0f, -10.0f, -10.0f, -10.0f, -10.0f, -10.0f};

    int t0 = th * 2, t1 = th * 2 + 1;

    for (int it = 0; it < 16; ++it) {
        int bb = it & 1;
        if (it < 15) {   // prefetch next tile into the other buffer (overlaps compute)
            const half_t* kslab = khead + (size_t)(it + 1) * 8192;
            const half_t* vslab = vhead + (size_t)(it + 1) * 8192;
            half_t* Kd = (half_t*)(smem + (bb ^ 1) * 32768);
            half_t* Vd = (half_t*)(smem + 16384 + (bb ^ 1) * 32768);
#pragma unroll
            for (int j = 0; j < 2; ++j) {
                int s = wave * 2 + j;
                gload_lds16(kslab + s * 512 + lane * 8, Kd + s * 512);
                gload_lds16(vslab + s * 512 + lane * 8, Vd + s * 512);
            }
        }
        half_t* Ks  = (half_t*)(smem + bb * 32768);
        half_t* VTs = (half_t*)(smem + 16384 + bb * 32768);

        // ---- QK for both k-subtiles, interleaved (sv1's MFMAs hide sv0's tail) ----
        f32x16 sv0 = sinit, sv1 = sinit;
        __builtin_amdgcn_s_setprio(1);
#pragma unroll
        for (int ks = 0; ks < 4; ++ks) {
            half8 kf0 = *(const half8*)(Ks + ((size_t)((2 * ks + hi) * 128 + t0 * 32 + ml)) * 8);
            half8 kf1 = *(const half8*)(Ks + ((size_t)((2 * ks + hi) * 128 + t1 * 32 + ml)) * 8);
            sv0 = MFMA32(kf0, qf[ks], sv0);
            sv1 = MFMA32(kf1, qf[ks], sv1);
        }
        __builtin_amdgcn_s_setprio(0);

        // ---- SM0: softmax of sv0 (VALU/TRANS), feeds lsumA only ----
        unsigned pkv0[8];
        {
            float lsA = lsumA;
#pragma unroll
            for (int j = 0; j < 8; ++j) {
                float pa = EXP2F(sv0[2 * j]);
                float pb = EXP2F(sv0[2 * j + 1]);
#if __has_builtin(__builtin_amdgcn_cvt_pkrtz)
                fp16x2 h2 = __builtin_amdgcn_cvt_pkrtz(pa, pb);
#else
                fp16x2 h2; h2.x = (__fp16)pa; h2.y = (__fp16)pb;
#endif
                pkv0[j] = __builtin_bit_cast(unsigned, h2);
#if __has_builtin(__builtin_amdgcn_fdot2)
                lsA = __builtin_amdgcn_fdot2(h2, one2, lsA, false);
#else
                lsA += pa + pb;
#endif
            }
            lsumA = lsA;
        }

        // ---- PV0 (MFMA; SM1's VALU below issues under these) ----
#pragma unroll
        for (int kp = 0; kp < 2; ++kp) {
            union { unsigned u[4]; half8 h; } fr;
#if __has_builtin(__builtin_amdgcn_permlane32_swap)
            uint2v w0 = __builtin_amdgcn_permlane32_swap(pkv0[4 * kp + 0], pkv0[4 * kp + 2], false, false);
            uint2v w1 = __builtin_amdgcn_permlane32_swap(pkv0[4 * kp + 1], pkv0[4 * kp + 3], false, false);
            fr.u[0] = w0.x; fr.u[1] = w1.x; fr.u[2] = w0.y; fr.u[3] = w1.y;
#else
            unsigned e0 = pkv0[4 * kp + 0], e1 = pkv0[4 * kp + 1];
            unsigned o0 = pkv0[4 * kp + 2], o1 = pkv0[4 * kp + 3];
            unsigned s0u = hi ? e0 : o0, s1u = hi ? e1 : o1;
            unsigned k0u = hi ? o0 : e0, k1u = hi ? o1 : e1;
            unsigned r0 = __shfl_xor(s0u, 32, 64);
            unsigned r1 = __shfl_xor(s1u, 32, 64);
            fr.u[0] = hi ? r0 : k0u; fr.u[1] = hi ? r1 : k1u;
            fr.u[2] = hi ? k0u : r0; fr.u[3] = hi ? k1u : r1;
#endif
            __builtin_amdgcn_s_setprio(1);
#pragma unroll
            for (int dt = 0; dt < 2; ++dt) {
                half8 vf = *(const half8*)(VTs + ((size_t)((4 * t0 + 2 * kp + hi) * 64 + dt * 32 + ml)) * 8);
                oacc[dt] = MFMA32(fr.h, vf, oacc[dt]);
            }
            __builtin_amdgcn_s_setprio(0);
        }

        // ---- SM1: softmax of sv1, feeds lsumB only (overlaps PV0 drain) ----
        unsigned pkv1[8];
        {
            float lsB = lsumB;
#pragma unroll
            for (int j = 0; j < 8; ++j) {
                float pa = EXP2F(sv1[2 * j]);
                float pb = EXP2F(sv1[2 * j + 1]);
#if __has_builtin(__builtin_amdgcn_cvt_pkrtz)
                fp16x2 h2 = __builtin_amdgcn_cvt_pkrtz(pa, pb);
#else
                fp16x2 h2; h2.x = (__fp16)pa; h2.y = (__fp16)pb;
#endif
                pkv1[j] = __builtin_bit_cast(unsigned, h2);
#if __has_builtin(__builtin_amdgcn_fdot2)
                lsB = __builtin_amdgcn_fdot2(h2, one2, lsB, false);
#else
                lsB += pa + pb;
#endif
            }
            lsumB = lsB;
        }

        // ---- PV1 ----
#pragma unroll
        for (int kp = 0; kp < 2; ++kp) {
            union { unsigned u[4]; half8 h; } fr;
#if __has_builtin(__builtin_amdgcn_permlane32_swap)
            uint2v w0 = __builtin_amdgcn_permlane32_swap(pkv1[4 * kp + 0], pkv1[4 * kp + 2], false, false);
            uint2v w1 = __builtin_amdgcn_permlane32_swap(pkv1[4 * kp + 1], pkv1[4 * kp + 3], false, false);
            fr.u[0] = w0.x; fr.u[1] = w1.x; fr.u[2] = w0.y; fr.u[3] = w1.y;
#else
            unsigned e0 = pkv1[4 * kp + 0], e1 = pkv1[4 * kp + 1];
            unsigned o0 = pkv1[4 * kp + 2], o1 = pkv1[4 * kp + 3];
            unsigned s0u = hi ? e0 : o0, s1u = hi ? e1 : o1;
            unsigned k0u = hi ? o0 : e0, k1u = hi ? o1 : e1;
            unsigned r0 = __shfl_xor(s0u, 32, 64);
            unsigned r1 = __shfl_xor(s1u, 32, 64);
            fr.u[0] = hi ? r0 : k0u; fr.u[1] = hi ? r1 : k1u;
            fr.u[2] = hi ? k0u : r0; fr.u[3] = hi ? k1u : r1;
#endif
            __builtin_amdgcn_s_setprio(1);
#pragma unroll
            for (int dt = 0; dt < 2; ++dt) {
                half8 vf = *(const half8*)(VTs + ((size_t)((4 * t1 + 2 * kp + hi) * 64 + dt * 32 + ml)) * 8);
                oacc[dt] = MFMA32(fr.h, vf, oacc[dt]);
            }
            __builtin_amdgcn_s_setprio(0);
        }

        __syncthreads();   // drains the it+1 prefetch (issued ~full compute phase ago)
    }

    // ---- epilogue: combine th partials, normalize, store ----
    float lsum = lsumA + lsumB;
    float lt = lsum + __shfl_xor(lsum, 32, 64);

    // Phase 1: combine O partials across th (per qq: 32q x 64d f32 = 8 KB)
    float* OB = (float*)(smem + (size_t)qq * 8192);
    if (th == 1) {
#pragma unroll
        for (int dt = 0; dt < 2; ++dt)
#pragma unroll
            for (int r = 0; r < 16; ++r) {
                int q = 4 * hi + (r & 3) + 8 * (r >> 2);
                OB[q * 64 + dt * 32 + ml] = oacc[dt][r];
            }
    }
    __syncthreads();
    if (th == 0) {
#pragma unroll
        for (int dt = 0; dt < 2; ++dt)
#pragma unroll
            for (int r = 0; r < 16; ++r) {
                int q = 4 * hi + (r & 3) + 8 * (r >> 2);
                oacc[dt][r] += OB[q * 64 + dt * 32 + ml];
            }
    }
    __syncthreads();
    // Phase 2: combine l (Lbuf = 512 B, above the OB region)
    float* Lbuf = (float*)(smem + 32768);                  // [128 q]
    if (th == 1 && hi == 0) Lbuf[qq * 32 + ml] = lt;
    __syncthreads();
    if (th == 0 && hi == 0) Lbuf[qq * 32 + ml] += lt;
    __syncthreads();
    // Phase 3: normalize with the correct per-row l and store blocked ctx
    if (th == 0) {
        half_t* cslab = ctx + ((size_t)((b_ * 16 + sq) * 16 + h)) * 8192;
#pragma unroll
        for (int dt = 0; dt < 2; ++dt)
#pragma unroll
            for (int r = 0; r < 16; ++r) {
                int qw = 4 * hi + (r & 3) + 8 * (r >> 2);
                int q = qq * 32 + qw;
                int d = dt * 32 + ml;
                float linv = __builtin_amdgcn_rcpf(Lbuf[q]);
                cslab[((d >> 3) * 128 + q) * 8 + (d & 7)] =
                    (half_t)(oacc[dt][r] * linv);
            }
    }
}

extern "C" void kernel_launch(void* const* d_in, const int* in_sizes, int n_in,
                              void* d_out, int out_size, void* d_ws, size_t ws_size,
                              hipStream_t stream)
{
    const float* qx = (const float*)d_in[0];
    const float* kx = (const float*)d_in[1];
    const float* vx = (const float*)d_in[2];
    const float* Wq = (const float*)d_in[3];
    const float* bq = (const float*)d_in[4];
    const float* Wk = (const float*)d_in[5];
    const float* bk = (const float*)d_in[6];
    const float* Wv = (const float*)d_in[7];
    const float* bv = (const float*)d_in[8];
    const float* Wo = (const float*)d_in[9];
    const float* bo = (const float*)d_in[10];
    float* out = (float*)d_out;

    half_t* ws = (half_t*)d_ws;
    const size_t NT = (size_t)4096 * 1024;
    half_t* qxh = ws;                           // blocked A: qx fp16
    half_t* kxh = qxh + NT;
    half_t* vxh = kxh + NT;
    half_t* wt = vxh + NT;                      // blocked W^T x4
    half_t* qh = wt + (size_t)4 * 1048576;      // per-head blocked Q (pre-scaled)
    half_t* kh = qh + NT;                       // per-head blocked K
    half_t* vtr = kh + NT;                      // per-head blocked V^T
    half_t* ctx = vtr + NT;                     // blocked ctx

    cvtw<<<dim3(512, 4), 256, 0, stream>>>(qx, kx, vx, Wq, Wk, Wv, Wo, qxh, kxh, vxh, wt);
    gemm_qkv<<<dim3(256, 1, 3), 256, 0, stream>>>(qxh, kxh, vxh, wt, bq, bk, bv, qh, kh, vtr);
    attn<<<dim3(512, 1, 1), 512, 0, stream>>>(qh, kh, vtr, ctx);
    gemm_out<<<dim3(512, 1, 1), 256, 0, stream>>>(ctx, wt + (size_t)3 * 1048576, bo, out);
}